// Round 7
// baseline (345.692 us; speedup 1.0000x reference)
//
#include <hip/hip_runtime.h>
#include <math.h>

// ---------------------------------------------------------------------------
// OptimizedProtoHyperFormer — round 7: K1 occupancy rewrite (2048 blocks,
// acc[4][8], 4-deep prefetch). Rest identical to round 6.
// B=32, IB=103, H=W=256, P=16, RB=8, DIM=192, DEPTH=3, FFH=384, NT=8192.
// ---------------------------------------------------------------------------

typedef __attribute__((ext_vector_type(8))) short bf16x8;
typedef __attribute__((ext_vector_type(4))) float f32x4;

__device__ __forceinline__ float wsum64(float v) {
#pragma unroll
  for (int o = 32; o > 0; o >>= 1) v += __shfl_xor(v, o, 64);
  return v;
}
__device__ __forceinline__ float sum16(float v) {
#pragma unroll
  for (int o = 8; o > 0; o >>= 1) v += __shfl_xor(v, o, 64);
  return v;
}
__device__ __forceinline__ float max16(float v) {
#pragma unroll
  for (int o = 8; o > 0; o >>= 1) v = fmaxf(v, __shfl_xor(v, o, 64));
  return v;
}
__device__ __forceinline__ float gelu_f(float x) {
  return 0.5f * x * (1.0f + erff(x * 0.7071067811865476f));
}
__device__ __forceinline__ ushort f2bf(float f) {
  union { float f; unsigned u; } v;
  v.f = f;
  unsigned r = v.u + 0x7FFFu + ((v.u >> 16) & 1u);
  return (ushort)(r >> 16);
}

// ---------------------------------------------------------------------------
// prep: bf16 transposes of all MFMA weights + band_w transpose.
// ---------------------------------------------------------------------------
__global__ __launch_bounds__(256) void prep_w(
    const float* __restrict__ qw, const float* __restrict__ vw,
    const float* __restrict__ f1w, const float* __restrict__ f2w,
    const float* __restrict__ r1_w, const float* __restrict__ r2_w,
    const float* __restrict__ key_w, const float* __restrict__ band_w,
    ushort* __restrict__ qwT, ushort* __restrict__ vwT,
    ushort* __restrict__ f1T, ushort* __restrict__ f2T,
    ushort* __restrict__ r1T, ushort* __restrict__ r2T,
    ushort* __restrict__ keyT, float* __restrict__ bandT) {
  const int i = blockIdx.x * 256 + threadIdx.x;
  if (i < 110592) {  // qw, vw: [3][192][192] -> [3][j][k]
    const int d = i / 36864, r = i % 36864;
    const int k = r / 192, c = r % 192;
    qwT[d * 36864 + c * 192 + k] = f2bf(qw[i]);
    vwT[d * 36864 + c * 192 + k] = f2bf(vw[i]);
  }
  if (i < 221184) {
    const int d = i / 73728, r = i % 73728;
    const int k = r / 384, j = r % 384;        // f1: [3][192][384] -> [3][384][192]
    f1T[d * 73728 + j * 192 + k] = f2bf(f1w[i]);
    const int k2 = r / 192, j2 = r % 192;      // f2: [3][384][192] -> [3][192][384]
    f2T[d * 73728 + j2 * 384 + k2] = f2bf(f2w[i]);
  }
  if (i < 24576) {  // r1: [192][128] -> [j:128][k:192]
    const int j = i / 192, k = i % 192;
    r1T[i] = f2bf(r1_w[k * 128 + j]);
  }
  if (i < 6144) {   // r2: [128][48] -> [j:48][k:128]
    const int j = i / 128, k = i % 128;
    r2T[i] = f2bf(r2_w[k * 48 + j]);
  }
  if (i < 43008) {  // key: [200][192] -> [j:192][k:224 padded]
    const int j = i / 224, k = i % 224;
    keyT[i] = (k < 200) ? f2bf(key_w[k * 192 + j]) : (ushort)0;
  }
  if (i < 824) {    // band_w: [8][103] -> [103][8]
    const int ch = i >> 3, c = i & 7;
    bandT[i] = band_w[c * 103 + ch];
  }
}

// ---------------------------------------------------------------------------
// K1: fused band-reduction (103->8) + depthwise patch conv.
// Grid: b(32) x ip(16) x colquarter(4) = 2048 blocks, 256 threads.
// Thread: 1 float4 per channel, acc[4][8]; 4-deep channel prefetch.
// ---------------------------------------------------------------------------
__global__ __launch_bounds__(256) void k1_band_dw(
    const float* __restrict__ x, const float* __restrict__ bandT,
    const float* __restrict__ band_b, const float* __restrict__ dw_w,
    float* __restrict__ dw_out) {
  const int blk = blockIdx.x;
  const int cq = blk & 3;
  const int ip = (blk >> 2) & 15;
  const int b = blk >> 6;
  const int t = threadIdx.x;
  const int row = t >> 4;    // row within patch strip, 0..15
  const int c16 = t & 15;    // float4 index within 64-col strip

  float acc[4][8];
#pragma unroll
  for (int e = 0; e < 4; ++e)
#pragma unroll
    for (int c = 0; c < 8; ++c) acc[e][c] = 0.f;

  const f32x4* xp = (const f32x4*)(x + (size_t)b * (103 * 65536) +
                                   (size_t)ip * 4096 + cq * 64) +
                    row * 64 + c16;
  const int CS = 16384;  // channel stride in f32x4

  auto body = [&](const f32x4 v, const int ch) {
    const f32x4 wA = *(const f32x4*)&bandT[ch * 8];
    const f32x4 wB = *(const f32x4*)&bandT[ch * 8 + 4];
    const float bw[8] = {wA.x, wA.y, wA.z, wA.w, wB.x, wB.y, wB.z, wB.w};
#pragma unroll
    for (int c = 0; c < 8; ++c) {
      acc[0][c] = fmaf(v.x, bw[c], acc[0][c]);
      acc[1][c] = fmaf(v.y, bw[c], acc[1][c]);
      acc[2][c] = fmaf(v.z, bw[c], acc[2][c]);
      acc[3][c] = fmaf(v.w, bw[c], acc[3][c]);
    }
  };

  f32x4 v0 = __builtin_nontemporal_load(xp + 0 * CS);
  f32x4 v1 = __builtin_nontemporal_load(xp + 1 * CS);
  f32x4 v2 = __builtin_nontemporal_load(xp + 2 * CS);
  f32x4 v3 = __builtin_nontemporal_load(xp + 3 * CS);
#pragma unroll 1
  for (int ch = 0; ch < 100; ch += 4) {
    const int p1 = min(ch + 5, 102), p2 = min(ch + 6, 102), p3 = min(ch + 7, 102);
    const f32x4 n0 = __builtin_nontemporal_load(xp + (ch + 4) * CS);
    const f32x4 n1 = __builtin_nontemporal_load(xp + p1 * CS);
    const f32x4 n2 = __builtin_nontemporal_load(xp + p2 * CS);
    const f32x4 n3 = __builtin_nontemporal_load(xp + p3 * CS);
    body(v0, ch);
    body(v1, ch + 1);
    body(v2, ch + 2);
    body(v3, ch + 3);
    v0 = n0; v1 = n1; v2 = n2; v3 = n3;
  }
  body(v0, 100);
  body(v1, 101);
  body(v2, 102);

  // depthwise weights + band bias, per-element then reduce to patch
  const int q0 = (c16 & 3) << 2;
  float dwt[8];
#pragma unroll
  for (int c = 0; c < 8; ++c) dwt[c] = 0.f;
#pragma unroll
  for (int e = 0; e < 4; ++e) {
#pragma unroll
    for (int c = 0; c < 8; ++c)
      dwt[c] = fmaf(dw_w[c * 256 + row * 16 + q0 + e], acc[e][c] + band_b[c],
                    dwt[c]);
  }
  // wave reduce over lane bits {0,1} (cols within patch) and {4,5} (rows)
#pragma unroll
  for (int c = 0; c < 8; ++c) {
    dwt[c] += __shfl_xor(dwt[c], 1, 64);
    dwt[c] += __shfl_xor(dwt[c], 2, 64);
    dwt[c] += __shfl_xor(dwt[c], 16, 64);
    dwt[c] += __shfl_xor(dwt[c], 32, 64);
  }
  __shared__ float part[4][4][8];  // [wave][jloc][c]
  const int w = t >> 6, lane = t & 63;
  if ((lane & 51) == 0) {  // lanes 0,4,8,12: one per jloc group
    const int jl = (lane >> 2) & 3;
#pragma unroll
    for (int c = 0; c < 8; ++c) part[w][jl][c] = dwt[c];
  }
  __syncthreads();
  if (t < 32) {
    const int jj = t >> 3, c = t & 7;
    const float s =
        part[0][jj][c] + part[1][jj][c] + part[2][jj][c] + part[3][jj][c];
    dw_out[(((size_t)b * 16 + ip) * 16 + cq * 4 + jj) * 8 + c] = s;
  }
}

// ---------------------------------------------------------------------------
// K2 (MFMA): pw+LN -> router r1/r2 -> top2 -> proto mix -> keysT bf16.
// 32 tokens/block, 256 blocks, 4 waves.
// ---------------------------------------------------------------------------
__global__ __launch_bounds__(256) void k2_mfma(
    const float* __restrict__ dw, const float* __restrict__ pw_w,
    const float* __restrict__ pe_ln_w, const float* __restrict__ pe_ln_b,
    const float* __restrict__ spec_proto, const float* __restrict__ spat_proto,
    const ushort* __restrict__ r1T, const float* __restrict__ r1_b,
    const ushort* __restrict__ r2T, const float* __restrict__ r2_b,
    const ushort* __restrict__ keyT, const float* __restrict__ pos_bias,
    float* __restrict__ xb_out, ushort* __restrict__ keysT) {
  const int t = threadIdx.x;
  const int lane = t & 63, wid = t >> 6;
  const int wm = wid >> 1, wn = wid & 1;
  const int l15 = lane & 15, lg4 = lane >> 4;
  const int tok0 = blockIdx.x * 32;
  const int rl = wm * 16 + 4 * lg4;
  const int b = blockIdx.x >> 3;
  const int n0 = (blockIdx.x & 7) * 32;

  __shared__ float dw8s[32][8];
  __shared__ __align__(16) ushort s_xn[32][200];
  __shared__ __align__(16) ushort s_w[192][40];
  __shared__ __align__(16) ushort s_h[32][200];
  __shared__ __align__(16) ushort s_mix[32][232];
  __shared__ float s_rl[32][48];
  __shared__ float topwS[32][4];
  __shared__ int   topiS[32][4];

  dw8s[t >> 3][t & 7] = dw[((size_t)tok0 + (t >> 3)) * 8 + (t & 7)];
  __syncthreads();

  // ---- phase 1: pw + LN -> xb fp32, s_xn bf16 ----
#pragma unroll
  for (int half = 0; half < 2; ++half) {
    const int tt = half * 16 + (t >> 4), lg = t & 15;
    float pre[12], sm = 0.f;
#pragma unroll
    for (int m = 0; m < 12; ++m) {
      const int d = lg + 16 * m;
      const f32x4 pa = *(const f32x4*)&pw_w[d * 8];
      const f32x4 pb = *(const f32x4*)&pw_w[d * 8 + 4];
      float p = pa.x * dw8s[tt][0] + pa.y * dw8s[tt][1] + pa.z * dw8s[tt][2] +
                pa.w * dw8s[tt][3] + pb.x * dw8s[tt][4] + pb.y * dw8s[tt][5] +
                pb.z * dw8s[tt][6] + pb.w * dw8s[tt][7];
      pre[m] = p;
      sm += p;
    }
    sm = sum16(sm);
    const float mean = sm * (1.f / 192.f);
    float vv = 0.f;
#pragma unroll
    for (int m = 0; m < 12; ++m) {
      const float d0 = pre[m] - mean;
      vv = fmaf(d0, d0, vv);
    }
    vv = sum16(vv);
    const float inv = rsqrtf(vv * (1.f / 192.f) + 1e-5f);
#pragma unroll
    for (int m = 0; m < 12; ++m) {
      const int d = lg + 16 * m;
      const float xv = (pre[m] - mean) * inv * pe_ln_w[d] + pe_ln_b[d];
      s_xn[tt][d] = f2bf(xv);
      xb_out[((size_t)tok0 + tt) * 192 + d] = xv;
    }
  }
  __syncthreads();

  // ---- phase 2: r1 (K=192 -> 128) + gelu -> s_h bf16 ----
  {
    f32x4 hacc[4];
#pragma unroll
    for (int f = 0; f < 4; ++f) hacc[f] = (f32x4){0.f, 0.f, 0.f, 0.f};
#pragma unroll 1
    for (int ks = 0; ks < 6; ++ks) {
#pragma unroll
      for (int i = 0; i < 2; ++i) {
        const int lin = t + 256 * i;
        const int row = lin >> 2, c8 = (lin & 3) * 8;
        *(uint4*)&s_w[row][c8] = *(const uint4*)&r1T[row * 192 + ks * 32 + c8];
      }
      __syncthreads();
      const bf16x8 a = *(const bf16x8*)&s_xn[wm * 16 + l15][ks * 32 + 8 * lg4];
#pragma unroll
      for (int f = 0; f < 4; ++f) {
        const bf16x8 bb = *(const bf16x8*)&s_w[wn * 64 + 16 * f + l15][8 * lg4];
        hacc[f] = __builtin_amdgcn_mfma_f32_16x16x32_bf16(a, bb, hacc[f], 0, 0, 0);
      }
      __syncthreads();
    }
#pragma unroll
    for (int f = 0; f < 4; ++f) {
      const int col = wn * 64 + 16 * f + l15;
#pragma unroll
      for (int reg = 0; reg < 4; ++reg)
        s_h[rl + reg][col] = f2bf(gelu_f(hacc[f][reg] + r1_b[col]));
    }
  }
  __syncthreads();

  // ---- phase 3: r2 (K=128 -> 48) -> s_rl fp32 ----
  {
    f32x4 racc[2];
    racc[0] = (f32x4){0.f, 0.f, 0.f, 0.f};
    racc[1] = (f32x4){0.f, 0.f, 0.f, 0.f};
#pragma unroll 1
    for (int ks = 0; ks < 4; ++ks) {
      if (t < 192) {
        const int row = t >> 2, c8 = (t & 3) * 8;
        *(uint4*)&s_w[row][c8] = *(const uint4*)&r2T[row * 128 + ks * 32 + c8];
      }
      __syncthreads();
      const bf16x8 a = *(const bf16x8*)&s_h[wm * 16 + l15][ks * 32 + 8 * lg4];
      if (wn == 0) {
#pragma unroll
        for (int f = 0; f < 2; ++f) {
          const bf16x8 bb = *(const bf16x8*)&s_w[16 * f + l15][8 * lg4];
          racc[f] = __builtin_amdgcn_mfma_f32_16x16x32_bf16(a, bb, racc[f], 0, 0, 0);
        }
      } else {
        const bf16x8 bb = *(const bf16x8*)&s_w[32 + l15][8 * lg4];
        racc[0] = __builtin_amdgcn_mfma_f32_16x16x32_bf16(a, bb, racc[0], 0, 0, 0);
      }
      __syncthreads();
    }
    if (wn == 0) {
#pragma unroll
      for (int f = 0; f < 2; ++f) {
        const int col = 16 * f + l15;
#pragma unroll
        for (int reg = 0; reg < 4; ++reg)
          s_rl[rl + reg][col] = racc[f][reg] + r2_b[col];
      }
    } else {
      const int col = 32 + l15;
#pragma unroll
      for (int reg = 0; reg < 4; ++reg)
        s_rl[rl + reg][col] = racc[0][reg] + r2_b[col];
    }
  }
  __syncthreads();

  // ---- phase 4: top-2 + tau softmax (fp32) ----
  if (t < 64) {
    const int tt = t >> 1, half = t & 1;
    const float* base = &s_rl[tt][half * 24];
    float v0 = -1e30f, v1 = -1e30f;
    int i0 = 0, i1 = 0;
    for (int k = 0; k < 24; ++k) {
      const float vv = base[k];
      if (vv > v0) { v1 = v0; i1 = i0; v0 = vv; i0 = k; }
      else if (vv > v1) { v1 = vv; i1 = k; }
    }
    const float tau = (float)(0.07 + 1e-8);
    const float e1 = expf((v1 - v0) / tau);
    const float inv = 1.f / (1.f + e1);
    topwS[tt][half * 2] = inv;
    topwS[tt][half * 2 + 1] = e1 * inv;
    topiS[tt][half * 2] = i0;
    topiS[tt][half * 2 + 1] = i1;
  }
  __syncthreads();

  // ---- phase 5: mixed prototypes s_mix[32][224 padded] bf16 ----
#pragma unroll
  for (int r = 0; r < 28; ++r) {
    const int f = t + 256 * r;  // 32*224 = 7168 exact
    const int tok = f / 224, c = f % 224;
    float val = 0.f;
    if (c < 8) {
      val = topwS[tok][0] * spec_proto[topiS[tok][0] * 8 + c] +
            topwS[tok][1] * spec_proto[topiS[tok][1] * 8 + c];
    } else if (c < 200) {
      const int cc = c - 8;
      val = topwS[tok][2] * spat_proto[topiS[tok][2] * 192 + cc] +
            topwS[tok][3] * spat_proto[topiS[tok][3] * 192 + cc];
    }
    s_mix[tok][c] = f2bf(val);
  }
  __syncthreads();

  // ---- phase 6: keys (K=224 -> 192) + pos_bias -> keysT[b][c][n] bf16 ----
  {
    f32x4 kacc[6];
#pragma unroll
    for (int f = 0; f < 6; ++f) kacc[f] = (f32x4){0.f, 0.f, 0.f, 0.f};
#pragma unroll 1
    for (int ks = 0; ks < 7; ++ks) {
#pragma unroll
      for (int i = 0; i < 3; ++i) {
        const int lin = t + 256 * i;
        const int row = lin >> 2, c8 = (lin & 3) * 8;
        *(uint4*)&s_w[row][c8] = *(const uint4*)&keyT[row * 224 + ks * 32 + c8];
      }
      __syncthreads();
      const bf16x8 a = *(const bf16x8*)&s_mix[wm * 16 + l15][ks * 32 + 8 * lg4];
#pragma unroll
      for (int f = 0; f < 6; ++f) {
        const bf16x8 bb = *(const bf16x8*)&s_w[wn * 96 + 16 * f + l15][8 * lg4];
        kacc[f] = __builtin_amdgcn_mfma_f32_16x16x32_bf16(a, bb, kacc[f], 0, 0, 0);
      }
      __syncthreads();
    }
#pragma unroll
    for (int f = 0; f < 6; ++f) {
      const int col = wn * 96 + 16 * f + l15;
#pragma unroll
      for (int reg = 0; reg < 4; ++reg)
        keysT[((size_t)b * 192 + col) * 256 + n0 + rl + reg] =
            f2bf(kacc[f][reg] + pos_bias[col]);
    }
  }
}

// ---------------------------------------------------------------------------
// K3a (MFMA): LN -> xn bf16; q,v; softmax(q) -> qs bf16; v -> vT[b][d][n] bf16.
// ---------------------------------------------------------------------------
__global__ __launch_bounds__(256) void k3a_mfma(
    const float* __restrict__ xb, const float* __restrict__ lnw,
    const float* __restrict__ lnb, const ushort* __restrict__ qwT,
    const ushort* __restrict__ vwT, ushort* __restrict__ qs_bf,
    ushort* __restrict__ vT, int depth) {
  const int t = threadIdx.x;
  const int lane = t & 63, wid = t >> 6;
  const int wm = wid >> 1, wn = wid & 1;
  const int l15 = lane & 15, lg4 = lane >> 4;
  const int tok0 = blockIdx.x * 32;
  const int b = blockIdx.x >> 3;
  const int n0 = (blockIdx.x & 7) * 32;

  __shared__ __align__(16) char smem[12800 + 30720];
  ushort (*s_xn)[200] = (ushort(*)[200])smem;
  ushort (*s_wq)[40] = (ushort(*)[40])(smem + 12800);
  ushort (*s_wv)[40] = (ushort(*)[40])(smem + 12800 + 15360);
  float (*s_q)[196] = (float(*)[196])(smem + 12800);

  const float* lw = lnw + depth * 192;
  const float* lb = lnb + depth * 192;
#pragma unroll
  for (int half = 0; half < 2; ++half) {
    const int tt = half * 16 + (t >> 4);
    const int lg = t & 15;
    const float* xrow = xb + ((size_t)tok0 + tt) * 192;
    float vals[12], sm = 0.f;
#pragma unroll
    for (int m = 0; m < 12; ++m) {
      vals[m] = xrow[lg + 16 * m];
      sm += vals[m];
    }
    sm = sum16(sm);
    const float mean = sm * (1.f / 192.f);
    float vv = 0.f;
#pragma unroll
    for (int m = 0; m < 12; ++m) {
      const float d0 = vals[m] - mean;
      vv = fmaf(d0, d0, vv);
    }
    vv = sum16(vv);
    const float inv = rsqrtf(vv * (1.f / 192.f) + 1e-5f);
#pragma unroll
    for (int m = 0; m < 12; ++m) {
      const int d = lg + 16 * m;
      s_xn[tt][d] = f2bf((vals[m] - mean) * inv * lw[d] + lb[d]);
    }
  }
  __syncthreads();

  f32x4 aq[6], av[6];
#pragma unroll
  for (int f = 0; f < 6; ++f) {
    aq[f] = (f32x4){0.f, 0.f, 0.f, 0.f};
    av[f] = (f32x4){0.f, 0.f, 0.f, 0.f};
  }
  const ushort* qbase = qwT + depth * 36864;
  const ushort* vbase = vwT + depth * 36864;
#pragma unroll 1
  for (int ks = 0; ks < 6; ++ks) {
#pragma unroll
    for (int i = 0; i < 3; ++i) {
      const int idx = t + 256 * i;
      const int row = idx >> 2, c4 = (idx & 3) * 8;
      *(uint4*)&s_wq[row][c4] = *(const uint4*)&qbase[row * 192 + ks * 32 + c4];
      *(uint4*)&s_wv[row][c4] = *(const uint4*)&vbase[row * 192 + ks * 32 + c4];
    }
    __syncthreads();
    const bf16x8 a = *(const bf16x8*)&s_xn[wm * 16 + l15][ks * 32 + 8 * lg4];
#pragma unroll
    for (int f = 0; f < 6; ++f) {
      const bf16x8 bq = *(const bf16x8*)&s_wq[wn * 96 + 16 * f + l15][8 * lg4];
      const bf16x8 bv = *(const bf16x8*)&s_wv[wn * 96 + 16 * f + l15][8 * lg4];
      aq[f] = __builtin_amdgcn_mfma_f32_16x16x32_bf16(a, bq, aq[f], 0, 0, 0);
      av[f] = __builtin_amdgcn_mfma_f32_16x16x32_bf16(a, bv, av[f], 0, 0, 0);
    }
    __syncthreads();
  }

  const int rl = wm * 16 + 4 * lg4;
#pragma unroll
  for (int f = 0; f < 6; ++f) {
    const int col = wn * 96 + 16 * f + l15;
#pragma unroll
    for (int reg = 0; reg < 4; ++reg) {
      vT[((size_t)b * 192 + col) * 256 + n0 + rl + reg] = f2bf(av[f][reg]);
      s_q[rl + reg][col] = aq[f][reg];
    }
  }
  __syncthreads();

#pragma unroll
  for (int half = 0; half < 2; ++half) {
    const int tt = half * 16 + (t >> 4);
    const int lg = t & 15;
    float vals[12], mx = -1e30f;
#pragma unroll
    for (int m = 0; m < 12; ++m) {
      vals[m] = s_q[tt][lg + 16 * m];
      mx = fmaxf(mx, vals[m]);
    }
    mx = max16(mx);
    float s = 0.f;
#pragma unroll
    for (int m = 0; m < 12; ++m) {
      vals[m] = expf(vals[m] - mx);
      s += vals[m];
    }
    s = sum16(s);
    const float inv = 1.f / s;
#pragma unroll
    for (int m = 0; m < 12; ++m)
      qs_bf[((size_t)tok0 + tt) * 192 + lg + 16 * m] = f2bf(vals[m] * inv);
  }
}

// ---------------------------------------------------------------------------
// K3b (MFMA): KV^T[b][d][c] = sum_n vT[b][d][n] * keysT[b][c][n], K=256.
// Grid: 32 batches x 6 d-tiles = 192 blocks, 4 waves, output kvT bf16.
// ---------------------------------------------------------------------------
__global__ __launch_bounds__(256) void k3b_mfma(
    const ushort* __restrict__ vT, const ushort* __restrict__ keysT,
    ushort* __restrict__ kvT) {
  const int t = threadIdx.x;
  const int lane = t & 63, wid = t >> 6;
  const int wm = wid >> 1, wn = wid & 1;
  const int l15 = lane & 15, lg4 = lane >> 4;
  const int b = blockIdx.x / 6;
  const int d0 = (blockIdx.x % 6) * 32;

  __shared__ __align__(16) ushort s_a[32][264];  // vT tile: 32 d-rows x 256 n
  __shared__ __align__(16) ushort s_w[192][40];  // keysT stage: 192 c x 32 n

  const ushort* vbase = vT + ((size_t)b * 192 + d0) * 256;
#pragma unroll
  for (int i = 0; i < 4; ++i) {
    const int idx = t + 256 * i;
    const int row = idx >> 5, c8 = (idx & 31) * 8;
    *(uint4*)&s_a[row][c8] = *(const uint4*)&vbase[row * 256 + c8];
  }

  f32x4 acc[6];
#pragma unroll
  for (int f = 0; f < 6; ++f) acc[f] = (f32x4){0.f, 0.f, 0.f, 0.f};
  const ushort* kbase = keysT + (size_t)b * 192 * 256;
#pragma unroll 1
  for (int ks = 0; ks < 8; ++ks) {
#pragma unroll
    for (int i = 0; i < 3; ++i) {
      const int idx = t + 256 * i;
      const int row = idx >> 2, c4 = (idx & 3) * 8;
      *(uint4*)&s_w[row][c4] = *(const uint4*)&kbase[row * 256 + ks * 32 + c4];
    }
    __syncthreads();
    const bf16x8 a = *(const bf16x8*)&s_a[wm * 16 + l15][ks * 32 + 8 * lg4];
#pragma unroll
    for (int f = 0; f < 6; ++f) {
      const bf16x8 bb = *(const bf16x8*)&s_w[wn * 96 + 16 * f + l15][8 * lg4];
      acc[f] = __builtin_amdgcn_mfma_f32_16x16x32_bf16(a, bb, acc[f], 0, 0, 0);
    }
    __syncthreads();
  }

  const int rl = wm * 16 + 4 * lg4;
#pragma unroll
  for (int f = 0; f < 6; ++f) {
    const int col = wn * 96 + 16 * f + l15;
#pragma unroll
    for (int reg = 0; reg < 4; ++reg)
      kvT[((size_t)b * 192 + d0 + rl + reg) * 192 + col] = f2bf(acc[f][reg]);
  }
}

// ---------------------------------------------------------------------------
// K3c (MFMA): o1 = qs@KV; residual; LN; FFN; residual.
// ---------------------------------------------------------------------------
__global__ __launch_bounds__(256) void k3c_mfma(
    float* __restrict__ xb, const ushort* __restrict__ qs_bf,
    const ushort* __restrict__ kvT, const float* __restrict__ lnw,
    const float* __restrict__ lnb, const ushort* __restrict__ f1T,
    const ushort* __restrict__ f2T, const float* __restrict__ f1b,
    const float* __restrict__ f2b, const float* __restrict__ g1,
    const float* __restrict__ g2, int depth) {
  const int t = threadIdx.x;
  const int lane = t & 63, wid = t >> 6;
  const int wm = wid >> 1, wn = wid & 1;
  const int l15 = lane & 15, lg4 = lane >> 4;
  const int tok0 = blockIdx.x * 32;
  const int b = blockIdx.x >> 3;

  __shared__ __align__(16) char smem[12800 + 15360 + 12800 + 512];
  ushort (*s_a)[200] = (ushort(*)[200])smem;
  ushort (*s_w)[40] = (ushort(*)[40])(smem + 12800);
  ushort (*s_ff)[200] = (ushort(*)[200])(smem + 12800 + 15360);
  float (*s_red)[4] = (float(*)[4])(smem + 12800 + 15360 + 12800);

#pragma unroll
  for (int i = 0; i < 3; ++i) {
    const int idx = t + 256 * i;
    const int row = idx / 24, c8 = (idx % 24) * 8;
    *(uint4*)&s_a[row][c8] = *(const uint4*)&qs_bf[((size_t)tok0 + row) * 192 + c8];
  }
  __syncthreads();

  f32x4 o1[6];
#pragma unroll
  for (int f = 0; f < 6; ++f) o1[f] = (f32x4){0.f, 0.f, 0.f, 0.f};
  const ushort* kvb = kvT + (size_t)b * 36864;
#pragma unroll 1
  for (int ks = 0; ks < 6; ++ks) {
#pragma unroll
    for (int i = 0; i < 3; ++i) {
      const int idx = t + 256 * i;
      const int row = idx >> 2, c4 = (idx & 3) * 8;
      *(uint4*)&s_w[row][c4] = *(const uint4*)&kvb[row * 192 + ks * 32 + c4];
    }
    __syncthreads();
    const bf16x8 a = *(const bf16x8*)&s_a[wm * 16 + l15][ks * 32 + 8 * lg4];
#pragma unroll
    for (int f = 0; f < 6; ++f) {
      const bf16x8 bb = *(const bf16x8*)&s_w[wn * 96 + 16 * f + l15][8 * lg4];
      o1[f] = __builtin_amdgcn_mfma_f32_16x16x32_bf16(a, bb, o1[f], 0, 0, 0);
    }
    __syncthreads();
  }

  const float* g1p = g1 + depth * 192;
  const float* lw = lnw + depth * 192;
  const float* lb = lnb + depth * 192;
  const int rl = wm * 16 + 4 * lg4;
  float xbn[6][4];
  float psum[4] = {0.f, 0.f, 0.f, 0.f}, psq[4] = {0.f, 0.f, 0.f, 0.f};
#pragma unroll
  for (int f = 0; f < 6; ++f) {
    const int col = wn * 96 + 16 * f + l15;
#pragma unroll
    for (int reg = 0; reg < 4; ++reg) {
      const float xv =
          xb[((size_t)tok0 + rl + reg) * 192 + col] + o1[f][reg] * g1p[col];
      xbn[f][reg] = xv;
      psum[reg] += xv;
      psq[reg] = fmaf(xv, xv, psq[reg]);
    }
  }
#pragma unroll
  for (int reg = 0; reg < 4; ++reg) {
#pragma unroll
    for (int o = 8; o > 0; o >>= 1) {
      psum[reg] += __shfl_xor(psum[reg], o, 64);
      psq[reg] += __shfl_xor(psq[reg], o, 64);
    }
  }
  if (l15 == 0) {
#pragma unroll
    for (int reg = 0; reg < 4; ++reg) {
      s_red[rl + reg][wn] = psum[reg];
      s_red[rl + reg][2 + wn] = psq[reg];
    }
  }
  __syncthreads();
  float mean[4], inv[4];
#pragma unroll
  for (int reg = 0; reg < 4; ++reg) {
    const float s = s_red[rl + reg][0] + s_red[rl + reg][1];
    const float q = s_red[rl + reg][2] + s_red[rl + reg][3];
    mean[reg] = s * (1.f / 192.f);
    const float var = q * (1.f / 192.f) - mean[reg] * mean[reg];
    inv[reg] = rsqrtf(var + 1e-5f);
  }
#pragma unroll
  for (int f = 0; f < 6; ++f) {
    const int col = wn * 96 + 16 * f + l15;
#pragma unroll
    for (int reg = 0; reg < 4; ++reg)
      s_a[rl + reg][col] =
          f2bf((xbn[f][reg] - mean[reg]) * inv[reg] * lw[col] + lb[col]);
  }
  __syncthreads();

  f32x4 o2[6];
#pragma unroll
  for (int f = 0; f < 6; ++f) o2[f] = (f32x4){0.f, 0.f, 0.f, 0.f};
#pragma unroll 1
  for (int h = 0; h < 2; ++h) {
    f32x4 hh[6];
#pragma unroll
    for (int f = 0; f < 6; ++f) hh[f] = (f32x4){0.f, 0.f, 0.f, 0.f};
    const ushort* f1base = f1T + depth * 73728 + h * 36864;
#pragma unroll 1
    for (int ks = 0; ks < 6; ++ks) {
#pragma unroll
      for (int i = 0; i < 3; ++i) {
        const int idx = t + 256 * i;
        const int row = idx >> 2, c4 = (idx & 3) * 8;
        *(uint4*)&s_w[row][c4] = *(const uint4*)&f1base[row * 192 + ks * 32 + c4];
      }
      __syncthreads();
      const bf16x8 a = *(const bf16x8*)&s_a[wm * 16 + l15][ks * 32 + 8 * lg4];
#pragma unroll
      for (int f = 0; f < 6; ++f) {
        const bf16x8 bb = *(const bf16x8*)&s_w[wn * 96 + 16 * f + l15][8 * lg4];
        hh[f] = __builtin_amdgcn_mfma_f32_16x16x32_bf16(a, bb, hh[f], 0, 0, 0);
      }
      __syncthreads();
    }
    const float* b1p = f1b + depth * 384 + h * 192;
#pragma unroll
    for (int f = 0; f < 6; ++f) {
      const int col = wn * 96 + 16 * f + l15;
#pragma unroll
      for (int reg = 0; reg < 4; ++reg)
        s_ff[rl + reg][col] = f2bf(gelu_f(hh[f][reg] + b1p[col]));
    }
    __syncthreads();
    const ushort* f2base = f2T + depth * 73728;
#pragma unroll 1
    for (int ks2 = 0; ks2 < 6; ++ks2) {
#pragma unroll
      for (int i = 0; i < 3; ++i) {
        const int idx = t + 256 * i;
        const int row = idx >> 2, c4 = (idx & 3) * 8;
        *(uint4*)&s_w[row][c4] =
            *(const uint4*)&f2base[row * 384 + h * 192 + ks2 * 32 + c4];
      }
      __syncthreads();
      const bf16x8 a = *(const bf16x8*)&s_ff[wm * 16 + l15][ks2 * 32 + 8 * lg4];
#pragma unroll
      for (int f = 0; f < 6; ++f) {
        const bf16x8 bb = *(const bf16x8*)&s_w[wn * 96 + 16 * f + l15][8 * lg4];
        o2[f] = __builtin_amdgcn_mfma_f32_16x16x32_bf16(a, bb, o2[f], 0, 0, 0);
      }
      __syncthreads();
    }
  }

  const float* b2p = f2b + depth * 192;
  const float* g2p = g2 + depth * 192;
#pragma unroll
  for (int f = 0; f < 6; ++f) {
    const int col = wn * 96 + 16 * f + l15;
#pragma unroll
    for (int reg = 0; reg < 4; ++reg)
      xb[((size_t)tok0 + rl + reg) * 192 + col] =
          xbn[f][reg] + (o2[f][reg] + b2p[col]) * g2p[col];
  }
}

// ---------------------------------------------------------------------------
// K4: feat = LN(mean_n xb); out = feat @ head_w + head_b.
// ---------------------------------------------------------------------------
__global__ __launch_bounds__(192) void k4_head(
    const float* __restrict__ xb, const float* __restrict__ flnw,
    const float* __restrict__ flnb, const float* __restrict__ hw,
    const float* __restrict__ hb, float* __restrict__ out) {
  const int b = blockIdx.x, t = threadIdx.x;
  const int w = t >> 6, lane = t & 63;
  float s = 0.f;
  const float* base = xb + (size_t)b * 256 * 192 + t;
#pragma unroll 4
  for (int n = 0; n < 256; ++n) s += base[n * 192];
  const float feat_pre = s * (1.f / 256.f);
  __shared__ float red[3];
  __shared__ float feat[192];
  float sm = wsum64(feat_pre);
  if (lane == 0) red[w] = sm;
  __syncthreads();
  const float mean = (red[0] + red[1] + red[2]) * (1.f / 192.f);
  __syncthreads();
  const float dd = feat_pre - mean;
  sm = wsum64(dd * dd);
  if (lane == 0) red[w] = sm;
  __syncthreads();
  const float var = (red[0] + red[1] + red[2]) * (1.f / 192.f);
  feat[t] = dd * rsqrtf(var + 1e-5f) * flnw[t] + flnb[t];
  __syncthreads();
  if (t < 9) {
    float a = hb[t];
    for (int d = 0; d < 192; ++d) a = fmaf(feat[d], hw[d * 9 + t], a);
    out[b * 9 + t] = a;
  }
}

// ---------------------------------------------------------------------------
extern "C" void kernel_launch(void* const* d_in, const int* in_sizes, int n_in,
                              void* d_out, int out_size, void* d_ws, size_t ws_size,
                              hipStream_t stream) {
  (void)in_sizes; (void)n_in; (void)out_size; (void)ws_size;
  const float* x          = (const float*)d_in[0];
  const float* band_w     = (const float*)d_in[1];
  const float* band_b     = (const float*)d_in[2];
  const float* dw_w       = (const float*)d_in[3];
  const float* pw_w       = (const float*)d_in[4];
  const float* pe_ln_w    = (const float*)d_in[5];
  const float* pe_ln_b    = (const float*)d_in[6];
  const float* spec_proto = (const float*)d_in[7];
  const float* spat_proto = (const float*)d_in[8];
  const float* r1_w       = (const float*)d_in[9];
  const float* r1_b       = (const float*)d_in[10];
  const float* r2_w       = (const float*)d_in[11];
  const float* r2_b       = (const float*)d_in[12];
  const float* key_w      = (const float*)d_in[13];
  const float* pos_bias   = (const float*)d_in[14];
  const float* blk_ln_w   = (const float*)d_in[15];
  const float* blk_ln_b   = (const float*)d_in[16];
  const float* blk_q_w    = (const float*)d_in[17];
  const float* blk_v_w    = (const float*)d_in[18];
  const float* blk_f1_w   = (const float*)d_in[19];
  const float* blk_f1_b   = (const float*)d_in[20];
  const float* blk_f2_w   = (const float*)d_in[21];
  const float* blk_f2_b   = (const float*)d_in[22];
  const float* blk_g1     = (const float*)d_in[23];
  const float* blk_g2     = (const float*)d_in[24];
  const float* fin_ln_w   = (const float*)d_in[25];
  const float* fin_ln_b   = (const float*)d_in[26];
  const float* head_w     = (const float*)d_in[27];
  const float* head_b     = (const float*)d_in[28];

  float* ws    = (float*)d_ws;
  float* dw    = ws;                   //    65,536 f32
  float* xbuf  = dw + 65536;           // 1,572,864 f32
  float* bandT = xbuf + 1572864;       //     1,024 f32 (824 used)
  ushort* ush    = (ushort*)(bandT + 1024);
  ushort* qs_bf  = ush;                // 1,572,864
  ushort* kvT    = qs_bf + 1572864;    // 1,179,648
  ushort* keysT  = kvT + 1179648;      // 1,572,864
  ushort* vT     = keysT + 1572864;    // 1,572,864
  ushort* qwT    = vT + 1572864;       //   110,592
  ushort* vwT    = qwT + 110592;       //   110,592
  ushort* f1T    = vwT + 110592;       //   221,184
  ushort* f2T    = f1T + 221184;       //   221,184
  ushort* r1T    = f2T + 221184;       //    24,576
  ushort* r2T    = r1T + 24576;        //     6,144
  ushort* keyT   = r2T + 6144;         //    43,008

  prep_w<<<864, 256, 0, stream>>>(blk_q_w, blk_v_w, blk_f1_w, blk_f2_w,
                                  r1_w, r2_w, key_w, band_w,
                                  qwT, vwT, f1T, f2T, r1T, r2T, keyT, bandT);
  k1_band_dw<<<2048, 256, 0, stream>>>(x, bandT, band_b, dw_w, dw);
  k2_mfma<<<256, 256, 0, stream>>>(dw, pw_w, pe_ln_w, pe_ln_b, spec_proto,
                                   spat_proto, r1T, r1_b, r2T, r2_b, keyT,
                                   pos_bias, xbuf, keysT);
  for (int d = 0; d < 3; ++d) {
    k3a_mfma<<<256, 256, 0, stream>>>(xbuf, blk_ln_w, blk_ln_b, qwT, vwT,
                                      qs_bf, vT, d);
    k3b_mfma<<<192, 256, 0, stream>>>(vT, keysT, kvT);
    k3c_mfma<<<256, 256, 0, stream>>>(xbuf, qs_bf, kvT, blk_ln_w, blk_ln_b,
                                      f1T, f2T, blk_f1_b, blk_f2_b, blk_g1,
                                      blk_g2, d);
  }
  k4_head<<<32, 192, 0, stream>>>(xbuf, fin_ln_w, fin_ln_b, head_w, head_b,
                                  (float*)d_out);
}